// Round 4
// baseline (465.859 us; speedup 1.0000x reference)
//
#include <hip/hip_runtime.h>
#include <math.h>

#define EPS   1e-12f
#define NOW_T 3600.0f
#define TDEC  3600.0f
#define K     5
#define D     768
#define GRID  2048   // 2048 blocks x 256 thr = 8 blocks/CU

typedef float vfloat4 __attribute__((ext_vector_type(4)));

__device__ __forceinline__ void consider(float (&v)[K], int (&ix)[K], float s, int i)
{
    if (s > v[K - 1]) {
        int j = K - 1;
        #pragma unroll
        for (int t = K - 1; t > 0; --t) {
            if (v[t - 1] < s) { v[t] = v[t - 1]; ix[t] = ix[t - 1]; j = t - 1; }
        }
        v[j] = s; ix[j] = i;
    }
}

// ---------------------------------------------------------------------------
// Fully fused: score (16 lanes/row, nontemporal float4 streams) + per-block
// top-5 + last-block-done global merge. Even contiguous row partition per
// block (imbalance <= 1 row). out[0..4]=scores, out[5..9]=indices as float.
// ---------------------------------------------------------------------------
__global__ __launch_bounds__(256) void fused_kernel(
    const float* __restrict__ q,      // [D]
    const float* __restrict__ loc,    // [2]
    const float* __restrict__ feat,   // [M][D]
    const float* __restrict__ mloc,   // [M][2]
    const float* __restrict__ meta,   // [M][4]
    float* __restrict__ cand_val,     // [GRID*K]
    int*   __restrict__ cand_idx,     // [GRID*K]
    unsigned* __restrict__ done_ctr,  // [1], pre-zeroed
    float* __restrict__ out,          // [2*K]
    int M)
{
    const int tid = threadIdx.x;
    const int c   = tid & 15;          // lane within 16-lane row group
    const int g   = tid >> 4;          // row group within block (0..15)

    // Query fragment: 48 floats/lane (16 lanes cover all 768 columns)
    const float* qp = q + c * 4;
    vfloat4 qv[12];
    float qss = 0.f;
    #pragma unroll
    for (int j = 0; j < 12; ++j) {
        qv[j] = *(const vfloat4*)(qp + j * 64);
        qss = fmaf(qv[j].x, qv[j].x, qss);
        qss = fmaf(qv[j].y, qv[j].y, qss);
        qss = fmaf(qv[j].z, qv[j].z, qss);
        qss = fmaf(qv[j].w, qv[j].w, qss);
    }
    #pragma unroll
    for (int m = 1; m < 16; m <<= 1) qss += __shfl_xor(qss, m);
    const float inv_qn = 1.0f / fmaxf(sqrtf(qss), EPS);

    const float lx = loc[0];
    const float ly = loc[1];

    // Even contiguous partition: first `rem` blocks get per+1 rows.
    const int per   = M / GRID;
    const int rem   = M - per * GRID;
    const int start = blockIdx.x * per + min((int)blockIdx.x, rem);
    const int count = per + (blockIdx.x < rem ? 1 : 0);
    const int end   = start + count;

    float v[K]; int ix[K];
    #pragma unroll
    for (int j = 0; j < K; ++j) { v[j] = -INFINITY; ix[j] = -1; }

    for (int base = start; base < end; base += 16) {
        const int row = base + g;
        float dot = 0.f, ss = 0.f;
        if (row < end) {
            const float* r = feat + (size_t)row * D + c * 4;
            #pragma unroll
            for (int j = 0; j < 12; ++j) {
                vfloat4 f = __builtin_nontemporal_load((const vfloat4*)(r + j * 64));
                dot = fmaf(f.x, qv[j].x, dot); ss = fmaf(f.x, f.x, ss);
                dot = fmaf(f.y, qv[j].y, dot); ss = fmaf(f.y, f.y, ss);
                dot = fmaf(f.z, qv[j].z, dot); ss = fmaf(f.z, f.z, ss);
                dot = fmaf(f.w, qv[j].w, dot); ss = fmaf(f.w, f.w, ss);
            }
        }
        #pragma unroll
        for (int m = 1; m < 16; m <<= 1) {
            dot += __shfl_xor(dot, m);
            ss  += __shfl_xor(ss,  m);
        }
        if (row < end && c == 0) {
            float sim = dot * inv_qn / fmaxf(sqrtf(ss), EPS);
            float2 ml = *(const float2*)(mloc + (size_t)row * 2);
            float4 md = *(const float4*)(meta + (size_t)row * 4);
            float dx = ml.x - lx, dy = ml.y - ly;
            float dist = sqrtf(dx * dx + dy * dy);
            float spatial  = 1.0f / (1.0f + dist);
            float temporal = expf((md.y - NOW_T) / TDEC);
            float s = (0.5f * sim + 0.3f * spatial + 0.2f * temporal) * md.x;
            consider(v, ix, s, row);
        }
    }

    // ---- Block epilogue: merge 16 leaders' lists, publish block top-5 ----
    __shared__ float sv[256 * K];
    __shared__ int   si[256 * K];
    __shared__ bool  amLast;

    if (c == 0) {
        #pragma unroll
        for (int j = 0; j < K; ++j) { sv[g * K + j] = v[j]; si[g * K + j] = ix[j]; }
    }
    __syncthreads();
    if (tid == 0) {
        float bv[K]; int bi[K];
        #pragma unroll
        for (int j = 0; j < K; ++j) { bv[j] = -INFINITY; bi[j] = -1; }
        for (int t = 0; t < 16 * K; ++t) consider(bv, bi, sv[t], si[t]);
        #pragma unroll
        for (int j = 0; j < K; ++j) {
            cand_val[blockIdx.x * K + j] = bv[j];
            cand_idx[blockIdx.x * K + j] = bi[j];
        }
        __threadfence();                       // release: candidates visible device-wide
        unsigned prev = atomicAdd(done_ctr, 1u);
        amLast = (prev == GRID - 1);
    }
    __syncthreads();
    if (!amLast) return;

    // ---- Last block: merge GRID*K = 10240 candidates with 256 threads ----
    __threadfence();                           // acquire: order counter before cand reads
    float mv2[K]; int mi2[K];
    #pragma unroll
    for (int j = 0; j < K; ++j) { mv2[j] = -INFINITY; mi2[j] = -1; }
    for (int i = tid; i < GRID * K; i += 256)
        consider(mv2, mi2, cand_val[i], cand_idx[i]);

    #pragma unroll
    for (int j = 0; j < K; ++j) { sv[tid * K + j] = mv2[j]; si[tid * K + j] = mi2[j]; }
    __syncthreads();

    for (int sz = 128; sz >= 1; sz >>= 1) {
        if (tid < sz) {
            const float* pv = &sv[(tid + sz) * K];
            const int*   pi = &si[(tid + sz) * K];
            float tv[K]; int ti[K];
            int a = 0, b = 0;
            #pragma unroll
            for (int j = 0; j < K; ++j) {
                bool takeA = (b >= K) || (a < K && mv2[a] >= pv[b]);
                if (takeA) { tv[j] = mv2[a]; ti[j] = mi2[a]; ++a; }
                else       { tv[j] = pv[b];  ti[j] = pi[b];  ++b; }
            }
            #pragma unroll
            for (int j = 0; j < K; ++j) {
                mv2[j] = tv[j]; mi2[j] = ti[j];
                sv[tid * K + j] = tv[j]; si[tid * K + j] = ti[j];
            }
        }
        __syncthreads();
    }

    if (tid == 0) {
        #pragma unroll
        for (int j = 0; j < K; ++j) {
            out[j]     = mv2[j];
            out[K + j] = (float)mi2[j];
        }
    }
}

extern "C" void kernel_launch(void* const* d_in, const int* in_sizes, int n_in,
                              void* d_out, int out_size, void* d_ws, size_t ws_size,
                              hipStream_t stream) {
    const float* q    = (const float*)d_in[0];   // [768]
    const float* loc  = (const float*)d_in[1];   // [2]
    const float* feat = (const float*)d_in[2];   // [M*768]
    const float* mloc = (const float*)d_in[3];   // [M*2]
    const float* meta = (const float*)d_in[4];   // [M*4]
    const int M = in_sizes[2] / D;

    float*    cand_val = (float*)d_ws;                               // GRID*K
    int*      cand_idx = (int*)((char*)d_ws + GRID * K * sizeof(float));
    unsigned* done_ctr = (unsigned*)((char*)d_ws + 2 * GRID * K * sizeof(float));

    hipMemsetAsync(done_ctr, 0, sizeof(unsigned), stream);
    fused_kernel<<<GRID, 256, 0, stream>>>(q, loc, feat, mloc, meta,
                                           cand_val, cand_idx, done_ctr,
                                           (float*)d_out, M);
}

// Round 5
// 434.581 us; speedup vs baseline: 1.0720x; 1.0720x over previous
//
#include <hip/hip_runtime.h>
#include <math.h>

#define EPS   1e-12f
#define NOW_T 3600.0f
#define TDEC  3600.0f
#define K     5
#define D     768
#define GRID  2048   // 2048 blocks x 256 thr = exact device thread capacity

__device__ __forceinline__ void consider(float (&v)[K], int (&ix)[K], float s, int i)
{
    if (s > v[K - 1]) {
        int j = K - 1;
        #pragma unroll
        for (int t = K - 1; t > 0; --t) {
            if (v[t - 1] < s) { v[t] = v[t - 1]; ix[t] = ix[t - 1]; j = t - 1; }
        }
        v[j] = s; ix[j] = i;
    }
}

// ---------------------------------------------------------------------------
// Fused score+block-topk: 16 lanes per row, grid-stride over row chunks.
// Group leader (c==0) keeps a private sorted top-5; block epilogue merges 16
// leaders' lists and writes one top-5 candidate set per block.
// NOTE (r4 post-mortem): plain loads (NOT nontemporal) and NO in-kernel
// global merge — 2048 same-address device-scope atomics serialized and cost
// ~30 us. Separate tiny merge kernel is cheaper.
// ---------------------------------------------------------------------------
__global__ __launch_bounds__(256) void score_topk_kernel(
    const float* __restrict__ q,      // [D]
    const float* __restrict__ loc,    // [2]
    const float* __restrict__ feat,   // [M][D]
    const float* __restrict__ mloc,   // [M][2]
    const float* __restrict__ meta,   // [M][4]
    float* __restrict__ cand_val,     // [GRID*K]
    int*   __restrict__ cand_idx,     // [GRID*K]
    int M)
{
    const int tid = threadIdx.x;
    const int c   = tid & 15;          // lane within 16-lane row group
    const int g   = tid >> 4;          // row group within block (0..15)

    // Query fragment: 48 floats/lane (16 lanes cover all 768 columns)
    const float* qp = q + c * 4;
    float4 qv[12];
    float qss = 0.f;
    #pragma unroll
    for (int j = 0; j < 12; ++j) {
        qv[j] = *(const float4*)(qp + j * 64);
        qss = fmaf(qv[j].x, qv[j].x, qss);
        qss = fmaf(qv[j].y, qv[j].y, qss);
        qss = fmaf(qv[j].z, qv[j].z, qss);
        qss = fmaf(qv[j].w, qv[j].w, qss);
    }
    #pragma unroll
    for (int m = 1; m < 16; m <<= 1) qss += __shfl_xor(qss, m);
    const float inv_qn = 1.0f / fmaxf(sqrtf(qss), EPS);

    const float lx = loc[0];
    const float ly = loc[1];

    float v[K]; int ix[K];
    #pragma unroll
    for (int j = 0; j < K; ++j) { v[j] = -INFINITY; ix[j] = -1; }

    for (int base = blockIdx.x * 16; base < M; base += GRID * 16) {
        const int row = base + g;
        float dot = 0.f, ss = 0.f;
        if (row < M) {
            const float* r = feat + (size_t)row * D + c * 4;
            #pragma unroll
            for (int j = 0; j < 12; ++j) {
                float4 f = *(const float4*)(r + j * 64);
                dot = fmaf(f.x, qv[j].x, dot); ss = fmaf(f.x, f.x, ss);
                dot = fmaf(f.y, qv[j].y, dot); ss = fmaf(f.y, f.y, ss);
                dot = fmaf(f.z, qv[j].z, dot); ss = fmaf(f.z, f.z, ss);
                dot = fmaf(f.w, qv[j].w, dot); ss = fmaf(f.w, f.w, ss);
            }
        }
        #pragma unroll
        for (int m = 1; m < 16; m <<= 1) {
            dot += __shfl_xor(dot, m);
            ss  += __shfl_xor(ss,  m);
        }
        if (row < M && c == 0) {
            float sim = dot * inv_qn / fmaxf(sqrtf(ss), EPS);
            float2 ml = *(const float2*)(mloc + (size_t)row * 2);
            float4 md = *(const float4*)(meta + (size_t)row * 4);
            float dx = ml.x - lx, dy = ml.y - ly;
            float dist = sqrtf(dx * dx + dy * dy);
            float spatial  = 1.0f / (1.0f + dist);
            float temporal = expf((md.y - NOW_T) / TDEC);
            float s = (0.5f * sim + 0.3f * spatial + 0.2f * temporal) * md.x;
            consider(v, ix, s, row);
        }
    }

    // Block epilogue: gather 16 leaders' sorted top-5, serial merge by thread 0.
    __shared__ float sv[16 * K];
    __shared__ int   si[16 * K];
    if (c == 0) {
        #pragma unroll
        for (int j = 0; j < K; ++j) { sv[g * K + j] = v[j]; si[g * K + j] = ix[j]; }
    }
    __syncthreads();
    if (tid == 0) {
        float bv[K]; int bi[K];
        #pragma unroll
        for (int j = 0; j < K; ++j) { bv[j] = -INFINITY; bi[j] = -1; }
        for (int t = 0; t < 16 * K; ++t) consider(bv, bi, sv[t], si[t]);
        #pragma unroll
        for (int j = 0; j < K; ++j) {
            cand_val[blockIdx.x * K + j] = bv[j];
            cand_idx[blockIdx.x * K + j] = bi[j];
        }
    }
}

// ---------------------------------------------------------------------------
// Merge kernel: single block over GRID*K = 10240 candidates (L2-resident).
// out[0..4] = scores (desc), out[5..9] = indices as float.
// ---------------------------------------------------------------------------
__global__ __launch_bounds__(1024) void merge_kernel(
    const float* __restrict__ cand_val, const int* __restrict__ cand_idx,
    int N, float* __restrict__ out)
{
    __shared__ float s_val[1024 * K];
    __shared__ int   s_idx[1024 * K];

    const int tid = threadIdx.x;
    float v[K]; int ix[K];
    #pragma unroll
    for (int j = 0; j < K; ++j) { v[j] = -INFINITY; ix[j] = -1; }

    for (int i = tid; i < N; i += 1024)
        consider(v, ix, cand_val[i], cand_idx[i]);

    #pragma unroll
    for (int j = 0; j < K; ++j) { s_val[tid * K + j] = v[j]; s_idx[tid * K + j] = ix[j]; }
    __syncthreads();

    for (int sz = 1024 >> 1; sz >= 1; sz >>= 1) {
        if (tid < sz) {
            const float* pv = &s_val[(tid + sz) * K];
            const int*   pi = &s_idx[(tid + sz) * K];
            float mv[K]; int mi[K];
            int a = 0, b = 0;
            #pragma unroll
            for (int j = 0; j < K; ++j) {
                bool takeA = (b >= K) || (a < K && v[a] >= pv[b]);
                if (takeA) { mv[j] = v[a];  mi[j] = ix[a]; ++a; }
                else       { mv[j] = pv[b]; mi[j] = pi[b]; ++b; }
            }
            #pragma unroll
            for (int j = 0; j < K; ++j) {
                v[j] = mv[j]; ix[j] = mi[j];
                s_val[tid * K + j] = v[j]; s_idx[tid * K + j] = ix[j];
            }
        }
        __syncthreads();
    }

    if (tid == 0) {
        #pragma unroll
        for (int j = 0; j < K; ++j) {
            out[j]     = v[j];
            out[K + j] = (float)ix[j];
        }
    }
}

extern "C" void kernel_launch(void* const* d_in, const int* in_sizes, int n_in,
                              void* d_out, int out_size, void* d_ws, size_t ws_size,
                              hipStream_t stream) {
    const float* q    = (const float*)d_in[0];   // [768]
    const float* loc  = (const float*)d_in[1];   // [2]
    const float* feat = (const float*)d_in[2];   // [M*768]
    const float* mloc = (const float*)d_in[3];   // [M*2]
    const float* meta = (const float*)d_in[4];   // [M*4]
    const int M = in_sizes[2] / D;

    float* cand_val = (float*)d_ws;                      // GRID*K floats (40 KB)
    int*   cand_idx = (int*)((char*)d_ws + GRID * K * sizeof(float));

    score_topk_kernel<<<GRID, 256, 0, stream>>>(q, loc, feat, mloc, meta,
                                                cand_val, cand_idx, M);
    merge_kernel<<<1, 1024, 0, stream>>>(cand_val, cand_idx, GRID * K, (float*)d_out);
}